// Round 9
// baseline (8767.326 us; speedup 1.0000x reference)
//
#include <hip/hip_runtime.h>
#include <hip/hip_bf16.h>
#include <hip/hip_fp16.h>
#include <math.h>

#define HH    1024
#define TT    64
#define NBAT  256
#define G3    3072
#define IN0   150
#define IN0P  160   // padded K for layer 0
#define NCLS  60
#define ENC_W 2048

typedef float  f32x4 __attribute__((ext_vector_type(4)));
typedef short  s16x8 __attribute__((ext_vector_type(8)));

#define GLOAD16(gsrc, ldst) \
  __builtin_amdgcn_global_load_lds((const __attribute__((address_space(1))) unsigned int*)(gsrc), \
                                   (__attribute__((address_space(3))) unsigned int*)(ldst), 16, 0, 0)

static __device__ inline short f2bf(float f) {
    __hip_bfloat16 h = __float2bfloat16(f);
    return *(short*)&h;
}

// ---------------- BatchNorm stats ----------------
__global__ void bigru_bn_stats(const float* __restrict__ x,
                               float* __restrict__ mean, float* __restrict__ istd) {
    int f = blockIdx.x;
    int tid = threadIdx.x;
    double s = 0.0, s2 = 0.0;
    for (int i = tid; i < NBAT * TT; i += blockDim.x) {
        float v = x[(size_t)i * IN0 + f];
        s += v; s2 += (double)v * v;
    }
    __shared__ double sh[256], sh2[256];
    sh[tid] = s; sh2[tid] = s2;
    __syncthreads();
    for (int off = 128; off > 0; off >>= 1) {
        if (tid < off) { sh[tid] += sh[tid + off]; sh2[tid] += sh2[tid + off]; }
        __syncthreads();
    }
    if (tid == 0) {
        double m = sh[0] / (NBAT * TT);
        double var = sh2[0] / (NBAT * TT) - m * m;
        mean[f] = (float)m;
        istd[f] = (float)(1.0 / sqrt(var + 1e-5));
    }
}

// ---------------- BN apply -> padded bf16 [16384][160] ----------------
__global__ void bigru_bn_apply_bf16(const float* __restrict__ x,
                                    const float* __restrict__ mean, const float* __restrict__ istd,
                                    const float* __restrict__ gamma, const float* __restrict__ beta,
                                    short* __restrict__ xn) {
    int idx = blockIdx.x * blockDim.x + threadIdx.x;
    if (idx >= NBAT * TT * IN0P) return;
    int f = idx % IN0P;
    int r = idx / IN0P;
    float v = 0.f;
    if (f < IN0) v = (x[(size_t)r * IN0 + f] - mean[f]) * istd[f] * gamma[f] + beta[f];
    xn[idx] = f2bf(v);
}

// ---------------- Convert w_ih_0 [2][3072][150] -> padded bf16 [2][3072][160] ----
__global__ void bigru_cvt_wih0(const float* __restrict__ src, short* __restrict__ dst) {
    int idx = blockIdx.x * blockDim.x + threadIdx.x;
    if (idx >= 2 * G3 * IN0P) return;
    int f = idx % IN0P;
    int r = idx / IN0P;
    float v = (f < IN0) ? src[(size_t)r * IN0 + f] : 0.f;
    dst[idx] = f2bf(v);
}

// ---------------- Generic f32 -> bf16 convert (n % 4 == 0) ----------------
__global__ void bigru_cvt4(const float* __restrict__ src, short* __restrict__ dst, int n4) {
    int i = blockIdx.x * blockDim.x + threadIdx.x;
    if (i >= n4) return;
    float4 v = ((const float4*)src)[i];
    short4 o;
    o.x = f2bf(v.x); o.y = f2bf(v.y); o.z = f2bf(v.z); o.w = f2bf(v.w);
    ((short4*)dst)[i] = o;
}

// ---------------- Bulk gi GEMM: C[2][Mchunk][3072] = A @ W^T + b_ih (fp16 out) ----
__global__ __launch_bounds__(256)
void bigru_gi_gemm(const short* __restrict__ Abase, int ldA, int K,
                   const short* __restrict__ W,       // [2][3072][K]
                   const float* __restrict__ b_ih,    // [2][3072]
                   __half* __restrict__ gi,           // [2][Mchunk][3072] fp16
                   int t0, int Mchunk) {
    int d    = blockIdx.z;
    int col0 = blockIdx.x * 128;
    int row0 = blockIdx.y * 128;

    __shared__ short As[128][32];
    __shared__ short Bs[128][32];

    int tid  = threadIdx.x;
    int lane = tid & 63;
    int w    = tid >> 6;
    int wm   = w & 1, wn = w >> 1;

    f32x4 acc[4][4];
    #pragma unroll
    for (int i = 0; i < 4; ++i)
        #pragma unroll
        for (int j = 0; j < 4; ++j)
            acc[i][j] = (f32x4){0.f, 0.f, 0.f, 0.f};

    const short* Wd = W + (size_t)d * G3 * K;
    int sr = lane >> 2;
    int sc = (lane & 3) * 8;

    for (int k0 = 0; k0 < K; k0 += 32) {
        #pragma unroll
        for (int q = 0; q < 2; ++q) {
            int r  = w * 32 + q * 16 + sr;            // 0..127
            int gr = row0 + r;
            int tt = gr >> 8, n = gr & 255;
            const short* ga = Abase + (size_t)(n * TT + t0 + tt) * ldA + k0 + sc;
            GLOAD16(ga, &As[w * 32 + q * 16][0]);
            const short* gb = Wd + (size_t)(col0 + r) * K + k0 + sc;
            GLOAD16(gb, &Bs[w * 32 + q * 16][0]);
        }
        __syncthreads();

        int fr = lane & 15, fq = (lane >> 4) * 8;
        s16x8 a[4], b[4];
        #pragma unroll
        for (int i = 0; i < 4; ++i) a[i] = *(const s16x8*)&As[wm * 64 + i * 16 + fr][fq];
        #pragma unroll
        for (int j = 0; j < 4; ++j) b[j] = *(const s16x8*)&Bs[wn * 64 + j * 16 + fr][fq];
        #pragma unroll
        for (int i = 0; i < 4; ++i)
            #pragma unroll
            for (int j = 0; j < 4; ++j)
                acc[i][j] = __builtin_amdgcn_mfma_f32_16x16x32_bf16(a[i], b[j], acc[i][j], 0, 0, 0);
        __syncthreads();
    }

    int fr = lane & 15, quad = lane >> 4;
    #pragma unroll
    for (int j = 0; j < 4; ++j) {
        int c = col0 + wn * 64 + j * 16 + fr;
        float bias = b_ih[d * G3 + c];
        #pragma unroll
        for (int i = 0; i < 4; ++i) {
            #pragma unroll
            for (int reg = 0; reg < 4; ++reg) {
                int r = row0 + wm * 64 + i * 16 + quad * 4 + reg;
                gi[((size_t)d * Mchunk + r) * G3 + c] = __float2half(acc[i][j][reg] + bias);
            }
        }
    }
}

// ---------------- Per-timestep recurrence kernel (v9) ----------------
// 128 blocks x 512 threads (8 waves). Block b: d=b&1, mt=(b>>1)&1, cg=b>>2
// owns 128 rows x 32 h-cols. Halves the A-broadcast (32 MB/step vs v8's 64):
// A loaded ONCE fully into registers (wave w: 16 rows, 32 x s16x8 = 128 VGPR,
// statically indexed) and reused across TWO W-phases of 16 cols each, staged
// into the same 96 KiB swizzled LDS. No A-ring, no manual vmcnt. W traffic
// unchanged (24.6 MB/step). 1 block/CU (96 KiB LDS) -> VGPR<=256 free.
__global__ __launch_bounds__(512, 2)
void bigru_step(const short* __restrict__ w_hh,     // [2][3072][1024] bf16
                const float* __restrict__ b_hh,     // [2][3072]
                const __half* __restrict__ gi,      // [2][Mchunk][3072] fp16
                float* __restrict__ h,              // [2][256][1024] fp32 master
                const short* __restrict__ hbf_in,   // [2][256][1024] bf16
                short* __restrict__ hbf_out,        // [2][256][1024] bf16
                float* __restrict__ enc,            // non-null only on last layer
                short* __restrict__ enc_bf,         // null on last layer
                int t, int ttl, int Mchunk) {
    __shared__ short Ws[48 * 1024];     // 96 KiB W slice (one 16-col phase)

    int b   = blockIdx.x;
    int d   = b & 1;
    int mt  = (b >> 1) & 1;
    int cg  = b >> 2;              // 0..31 -> 32 cols

    int tid  = threadIdx.x;
    int lane = tid & 63;
    int w    = tid >> 6;           // 0..7
    int fr   = lane & 15;
    int quad = lane >> 4;
    int sw   = fr & 7;

    int j0 = cg * 32;
    int row_base = mt * 128 + w * 16;   // wave owns 16 rows

    const short* Wd = w_hh + (size_t)d * G3 * HH;
    const short* hb = hbf_in + (size_t)d * NBAT * HH;

    // ---- stage W phase 0 (cols j0..j0+16) into LDS (swizzled src, linear dest) ----
    #pragma unroll
    for (int q = 0; q < 12; ++q) {
        int c  = w * 12 + q;               // 0..95
        int rr = c >> 1, kh = c & 1;       // rr: wrow 0..47, kh: half-row
        int g  = rr >> 4, jc = rr & 15;
        const short* src = Wd + (size_t)(g * HH + j0 + jc) * HH
                         + (size_t)(kh * 64 + (lane ^ (rr & 7))) * 8;
        GLOAD16(src, &Ws[rr * 1024 + kh * 512]);
    }

    // ---- A fully into registers: 32 x s16x8 (row = row_base+fr, k-slice quad*8) ----
    const short* asrc = hb + (size_t)(row_base + fr) * HH + quad * 8;
    s16x8 areg[32];
    #pragma unroll
    for (int c = 0; c < 32; ++c)
        areg[c] = *(const s16x8*)(asrc + c * 32);

    // ---- gi (fp16), h master, biases for BOTH phases (overlap W/A latency) ----
    float gir[2][4], giz[2][4], gin[2][4], hreg[2][4];
    float bhr[2], bhz[2], bhn[2];
    #pragma unroll
    for (int p = 0; p < 2; ++p) {
        int jcol = j0 + p * 16 + fr;
        bhr[p] = b_hh[d * G3 + jcol];
        bhz[p] = b_hh[d * G3 + HH + jcol];
        bhn[p] = b_hh[d * G3 + 2 * HH + jcol];
        size_t gb = ((size_t)d * Mchunk + (size_t)ttl * NBAT) * G3 + jcol;
        #pragma unroll
        for (int r = 0; r < 4; ++r) {
            int n = row_base + quad * 4 + r;
            size_t gg = gb + (size_t)n * G3;
            gir[p][r] = __half2float(gi[gg]);
            giz[p][r] = __half2float(gi[gg + HH]);
            gin[p][r] = __half2float(gi[gg + 2 * HH]);
            hreg[p][r] = h[((size_t)d * NBAT + n) * HH + jcol];
        }
    }

    f32x4 acc[2][3];
    #pragma unroll
    for (int p = 0; p < 2; ++p)
        #pragma unroll
        for (int g = 0; g < 3; ++g)
            acc[p][g] = (f32x4){0.f, 0.f, 0.f, 0.f};

    __syncthreads();   // drains W0 DMA + A loads + scalars

    // ---- phase 0 K-loop: pure registers + LDS ----
    #pragma unroll
    for (int c = 0; c < 32; ++c) {
        int ks = c * 4 + quad;
        #pragma unroll
        for (int g = 0; g < 3; ++g) {
            s16x8 bg = *(const s16x8*)&Ws[(g * 16 + fr) * 1024 + ((ks ^ sw) << 3)];
            acc[0][g] = __builtin_amdgcn_mfma_f32_16x16x32_bf16(areg[c], bg, acc[0][g], 0, 0, 0);
        }
    }

    __syncthreads();   // all waves done reading Ws phase 0

    // ---- stage W phase 1 (cols j0+16..j0+32) ----
    #pragma unroll
    for (int q = 0; q < 12; ++q) {
        int c  = w * 12 + q;
        int rr = c >> 1, kh = c & 1;
        int g  = rr >> 4, jc = rr & 15;
        const short* src = Wd + (size_t)(g * HH + j0 + 16 + jc) * HH
                         + (size_t)(kh * 64 + (lane ^ (rr & 7))) * 8;
        GLOAD16(src, &Ws[rr * 1024 + kh * 512]);
    }

    __syncthreads();   // drains W1 DMA

    // ---- phase 1 K-loop: A reused from registers ----
    #pragma unroll
    for (int c = 0; c < 32; ++c) {
        int ks = c * 4 + quad;
        #pragma unroll
        for (int g = 0; g < 3; ++g) {
            s16x8 bg = *(const s16x8*)&Ws[(g * 16 + fr) * 1024 + ((ks ^ sw) << 3)];
            acc[1][g] = __builtin_amdgcn_mfma_f32_16x16x32_bf16(areg[c], bg, acc[1][g], 0, 0, 0);
        }
    }

    // ---- gates + state update (both phases) ----
    short* ho = hbf_out + (size_t)d * NBAT * HH;
    #pragma unroll
    for (int p = 0; p < 2; ++p) {
        int jcol = j0 + p * 16 + fr;
        #pragma unroll
        for (int r = 0; r < 4; ++r) {
            int n = row_base + quad * 4 + r;
            float hrv = acc[p][0][r] + bhr[p];
            float hzv = acc[p][1][r] + bhz[p];
            float hnv = acc[p][2][r] + bhn[p];
            float rg = 1.f / (1.f + __expf(-(gir[p][r] + hrv)));
            float zg = 1.f / (1.f + __expf(-(giz[p][r] + hzv)));
            float ng = tanhf(gin[p][r] + rg * hnv);
            float hnew = (1.f - zg) * ng + zg * hreg[p][r];
            h[((size_t)d * NBAT + n) * HH + jcol] = hnew;
            ho[(size_t)n * HH + jcol] = f2bf(hnew);
            size_t eidx = ((size_t)n * TT + t) * ENC_W + (size_t)d * HH + jcol;
            if (enc_bf) enc_bf[eidx] = f2bf(hnew);
            if (enc)    enc[eidx]    = hnew;
        }
    }
}

// ---------------- FC head ----------------
__global__ void bigru_fc(const float* __restrict__ enc, const float* __restrict__ fc_w,
                         const float* __restrict__ fc_b, float* __restrict__ out) {
    int n = blockIdx.x;
    int tid = threadIdx.x;
    __shared__ float hbuf[ENC_W];
    for (int k = tid; k < ENC_W; k += blockDim.x)
        hbuf[k] = enc[(size_t)n * TT * ENC_W + (size_t)(TT - 1) * ENC_W + k];
    __syncthreads();
    if (tid < NCLS) {
        float acc = fc_b[tid];
        for (int k = 0; k < ENC_W; ++k)
            acc += hbuf[k] * fc_w[(size_t)tid * ENC_W + k];
        out[(size_t)n * NCLS + tid] = acc;
    }
}

extern "C" void kernel_launch(void* const* d_in, const int* in_sizes, int n_in,
                              void* d_out, int out_size, void* d_ws, size_t ws_size,
                              hipStream_t stream) {
    const float* x        = (const float*)d_in[0];
    const float* bn_gamma = (const float*)d_in[1];
    const float* bn_beta  = (const float*)d_in[2];
    const float* w_ih[3]  = {(const float*)d_in[3], (const float*)d_in[7],  (const float*)d_in[11]};
    const float* w_hh[3]  = {(const float*)d_in[4], (const float*)d_in[8],  (const float*)d_in[12]};
    const float* b_ih[3]  = {(const float*)d_in[5], (const float*)d_in[9],  (const float*)d_in[13]};
    const float* b_hh[3]  = {(const float*)d_in[6], (const float*)d_in[10], (const float*)d_in[14]};
    const float* fc_w     = (const float*)d_in[15];
    const float* fc_b     = (const float*)d_in[16];

    float* out = (float*)d_out;
    float* enc = out + NBAT * NCLS;                       // [256][64][2048] fp32

    // ---- workspace bump allocator (256B aligned) ----
    char* base = (char*)d_ws;
    size_t off = 0;
    auto alloc = [&](size_t bytes) {
        void* p = base + off;
        off += (bytes + 255) & ~(size_t)255;
        return p;
    };
    float* mean      = (float*)alloc(IN0 * 4);
    float* istd      = (float*)alloc(IN0 * 4);
    short* xn_bf     = (short*)alloc((size_t)NBAT * TT * IN0P * 2);
    short* wih0_bf   = (short*)alloc((size_t)2 * G3 * IN0P * 2);
    short* wih_bf    = (short*)alloc((size_t)2 * G3 * ENC_W * 2);
    short* whh_bf    = (short*)alloc((size_t)2 * G3 * HH * 2);
    float* h         = (float*)alloc((size_t)2 * NBAT * HH * 4);
    short* hbf       = (short*)alloc((size_t)2 * 2 * NBAT * HH * 2);  // double buffer
    short* enc_bf    = (short*)alloc((size_t)NBAT * TT * ENC_W * 2);
    size_t fixed = off;

    // pick largest Tc whose fp16 gi chunk fits in remaining ws
    int Tc = 1;
    for (int cand : {16, 8, 4, 2, 1}) {
        size_t gi_bytes = (size_t)2 * NBAT * cand * G3 * 2;
        if (fixed + gi_bytes + 1024 <= ws_size) { Tc = cand; break; }
    }
    __half* gi = (__half*)alloc((size_t)2 * NBAT * Tc * G3 * 2);
    int Mchunk = NBAT * Tc;

    // ---- BN ----
    bigru_bn_stats<<<IN0, 256, 0, stream>>>(x, mean, istd);
    bigru_bn_apply_bf16<<<(NBAT * TT * IN0P + 255) / 256, 256, 0, stream>>>(
        x, mean, istd, bn_gamma, bn_beta, xn_bf);

    // ---- weight conversions (layer-0 padded) ----
    bigru_cvt_wih0<<<(2 * G3 * IN0P + 255) / 256, 256, 0, stream>>>(w_ih[0], wih0_bf);

    for (int l = 0; l < 3; ++l) {
        if (l > 0) {
            int n4 = (2 * G3 * ENC_W) / 4;
            bigru_cvt4<<<(n4 + 255) / 256, 256, 0, stream>>>(w_ih[l], wih_bf, n4);
        }
        {
            int n4 = (2 * G3 * HH) / 4;
            bigru_cvt4<<<(n4 + 255) / 256, 256, 0, stream>>>(w_hh[l], whh_bf, n4);
        }
        hipMemsetAsync(h, 0, (size_t)2 * NBAT * HH * 4, stream);
        hipMemsetAsync(hbf, 0, (size_t)2 * 2 * NBAT * HH * 2, stream);

        const short* Abase = (l == 0) ? xn_bf : enc_bf;
        int ldA = (l == 0) ? IN0P : ENC_W;
        int K   = (l == 0) ? IN0P : ENC_W;
        const short* W = (l == 0) ? wih0_bf : wih_bf;
        float* enc_out   = (l == 2) ? enc : nullptr;
        short* encbf_out = (l == 2) ? nullptr : enc_bf;

        for (int t0 = 0; t0 < TT; t0 += Tc) {
            bigru_gi_gemm<<<dim3(G3 / 128, Mchunk / 128, 2), 256, 0, stream>>>(
                Abase, ldA, K, W, b_ih[l], gi, t0, Mchunk);

            for (int tt = 0; tt < Tc; ++tt) {
                int t = t0 + tt;
                const short* hin = hbf + (size_t)(t & 1) * 2 * NBAT * HH;
                short*       hout = hbf + (size_t)((t + 1) & 1) * 2 * NBAT * HH;
                bigru_step<<<dim3(128), 512, 0, stream>>>(
                    whh_bf, b_hh[l], gi, h, hin, hout,
                    enc_out, encbf_out, t, tt, Mchunk);
            }
        }
    }

    bigru_fc<<<NBAT, 256, 0, stream>>>(enc, fc_w, fc_b, out);
}

// Round 10
// 6789.473 us; speedup vs baseline: 1.2913x; 1.2913x over previous
//
#include <hip/hip_runtime.h>
#include <hip/hip_bf16.h>
#include <hip/hip_fp16.h>
#include <math.h>

#define HH    1024
#define TT    64
#define NBAT  256
#define G3    3072
#define IN0   150
#define IN0P  160   // padded K for layer 0
#define NCLS  60
#define ENC_W 2048

typedef float  f32x4 __attribute__((ext_vector_type(4)));
typedef short  s16x8 __attribute__((ext_vector_type(8)));

#define GLOAD16(gsrc, ldst) \
  __builtin_amdgcn_global_load_lds((const __attribute__((address_space(1))) unsigned int*)(gsrc), \
                                   (__attribute__((address_space(3))) unsigned int*)(ldst), 16, 0, 0)

static __device__ inline short f2bf(float f) {
    __hip_bfloat16 h = __float2bfloat16(f);
    return *(short*)&h;
}

// ---------------- BatchNorm stats ----------------
__global__ void bigru_bn_stats(const float* __restrict__ x,
                               float* __restrict__ mean, float* __restrict__ istd) {
    int f = blockIdx.x;
    int tid = threadIdx.x;
    double s = 0.0, s2 = 0.0;
    for (int i = tid; i < NBAT * TT; i += blockDim.x) {
        float v = x[(size_t)i * IN0 + f];
        s += v; s2 += (double)v * v;
    }
    __shared__ double sh[256], sh2[256];
    sh[tid] = s; sh2[tid] = s2;
    __syncthreads();
    for (int off = 128; off > 0; off >>= 1) {
        if (tid < off) { sh[tid] += sh[tid + off]; sh2[tid] += sh2[tid + off]; }
        __syncthreads();
    }
    if (tid == 0) {
        double m = sh[0] / (NBAT * TT);
        double var = sh2[0] / (NBAT * TT) - m * m;
        mean[f] = (float)m;
        istd[f] = (float)(1.0 / sqrt(var + 1e-5));
    }
}

// ---------------- BN apply -> padded bf16 [16384][160] ----------------
__global__ void bigru_bn_apply_bf16(const float* __restrict__ x,
                                    const float* __restrict__ mean, const float* __restrict__ istd,
                                    const float* __restrict__ gamma, const float* __restrict__ beta,
                                    short* __restrict__ xn) {
    int idx = blockIdx.x * blockDim.x + threadIdx.x;
    if (idx >= NBAT * TT * IN0P) return;
    int f = idx % IN0P;
    int r = idx / IN0P;
    float v = 0.f;
    if (f < IN0) v = (x[(size_t)r * IN0 + f] - mean[f]) * istd[f] * gamma[f] + beta[f];
    xn[idx] = f2bf(v);
}

// ---------------- Convert w_ih_0 [2][3072][150] -> padded bf16 [2][3072][160] ----
__global__ void bigru_cvt_wih0(const float* __restrict__ src, short* __restrict__ dst) {
    int idx = blockIdx.x * blockDim.x + threadIdx.x;
    if (idx >= 2 * G3 * IN0P) return;
    int f = idx % IN0P;
    int r = idx / IN0P;
    float v = (f < IN0) ? src[(size_t)r * IN0 + f] : 0.f;
    dst[idx] = f2bf(v);
}

// ---------------- Generic f32 -> bf16 convert (n % 4 == 0) ----------------
__global__ void bigru_cvt4(const float* __restrict__ src, short* __restrict__ dst, int n4) {
    int i = blockIdx.x * blockDim.x + threadIdx.x;
    if (i >= n4) return;
    float4 v = ((const float4*)src)[i];
    short4 o;
    o.x = f2bf(v.x); o.y = f2bf(v.y); o.z = f2bf(v.z); o.w = f2bf(v.w);
    ((short4*)dst)[i] = o;
}

// ---------------- Bulk gi GEMM: C[2][Mchunk][3072] = A @ W^T + b_ih (fp16 out) ----
__global__ __launch_bounds__(256)
void bigru_gi_gemm(const short* __restrict__ Abase, int ldA, int K,
                   const short* __restrict__ W,       // [2][3072][K]
                   const float* __restrict__ b_ih,    // [2][3072]
                   __half* __restrict__ gi,           // [2][Mchunk][3072] fp16
                   int t0, int Mchunk) {
    int d    = blockIdx.z;
    int col0 = blockIdx.x * 128;
    int row0 = blockIdx.y * 128;

    __shared__ short As[128][32];
    __shared__ short Bs[128][32];

    int tid  = threadIdx.x;
    int lane = tid & 63;
    int w    = tid >> 6;
    int wm   = w & 1, wn = w >> 1;

    f32x4 acc[4][4];
    #pragma unroll
    for (int i = 0; i < 4; ++i)
        #pragma unroll
        for (int j = 0; j < 4; ++j)
            acc[i][j] = (f32x4){0.f, 0.f, 0.f, 0.f};

    const short* Wd = W + (size_t)d * G3 * K;
    int sr = lane >> 2;
    int sc = (lane & 3) * 8;

    for (int k0 = 0; k0 < K; k0 += 32) {
        #pragma unroll
        for (int q = 0; q < 2; ++q) {
            int r  = w * 32 + q * 16 + sr;            // 0..127
            int gr = row0 + r;
            int tt = gr >> 8, n = gr & 255;
            const short* ga = Abase + (size_t)(n * TT + t0 + tt) * ldA + k0 + sc;
            GLOAD16(ga, &As[w * 32 + q * 16][0]);
            const short* gb = Wd + (size_t)(col0 + r) * K + k0 + sc;
            GLOAD16(gb, &Bs[w * 32 + q * 16][0]);
        }
        __syncthreads();

        int fr = lane & 15, fq = (lane >> 4) * 8;
        s16x8 a[4], b[4];
        #pragma unroll
        for (int i = 0; i < 4; ++i) a[i] = *(const s16x8*)&As[wm * 64 + i * 16 + fr][fq];
        #pragma unroll
        for (int j = 0; j < 4; ++j) b[j] = *(const s16x8*)&Bs[wn * 64 + j * 16 + fr][fq];
        #pragma unroll
        for (int i = 0; i < 4; ++i)
            #pragma unroll
            for (int j = 0; j < 4; ++j)
                acc[i][j] = __builtin_amdgcn_mfma_f32_16x16x32_bf16(a[i], b[j], acc[i][j], 0, 0, 0);
        __syncthreads();
    }

    int fr = lane & 15, quad = lane >> 4;
    #pragma unroll
    for (int j = 0; j < 4; ++j) {
        int c = col0 + wn * 64 + j * 16 + fr;
        float bias = b_ih[d * G3 + c];
        #pragma unroll
        for (int i = 0; i < 4; ++i) {
            #pragma unroll
            for (int reg = 0; reg < 4; ++reg) {
                int r = row0 + wm * 64 + i * 16 + quad * 4 + reg;
                gi[((size_t)d * Mchunk + r) * G3 + c] = __float2half(acc[i][j][reg] + bias);
            }
        }
    }
}

// ---------------- Per-timestep recurrence kernel (v10) ----------------
// = v9 structure with the VGPR-cap bug fixed:
//  * __launch_bounds__(512, 1): LDS (96 KiB) already limits to 1 block/CU;
//    v9's (512,2) capped the allocator at 128 VGPR -> areg[32] spilled to
//    scratch (VGPR_Count=128 in counters; 30ms outlier dispatch).
//  * gi/h/bias scalar loads moved BETWEEN phase 0 and phase 1 (issued with
//    W1's DMA): phase-0 peak ~185 reg, phase-1 ~230, both < 256.
// 128 blocks x 512 threads; block owns 128 rows x 32 cols; A in registers
// once, reused across two 16-col W-phases (halves A broadcast: 32 MB/step).
__global__ __launch_bounds__(512, 1)
void bigru_step(const short* __restrict__ w_hh,     // [2][3072][1024] bf16
                const float* __restrict__ b_hh,     // [2][3072]
                const __half* __restrict__ gi,      // [2][Mchunk][3072] fp16
                float* __restrict__ h,              // [2][256][1024] fp32 master
                const short* __restrict__ hbf_in,   // [2][256][1024] bf16
                short* __restrict__ hbf_out,        // [2][256][1024] bf16
                float* __restrict__ enc,            // non-null only on last layer
                short* __restrict__ enc_bf,         // null on last layer
                int t, int ttl, int Mchunk) {
    __shared__ short Ws[48 * 1024];     // 96 KiB W slice (one 16-col phase)

    int b   = blockIdx.x;
    int d   = b & 1;
    int mt  = (b >> 1) & 1;
    int cg  = b >> 2;              // 0..31 -> 32 cols

    int tid  = threadIdx.x;
    int lane = tid & 63;
    int w    = tid >> 6;           // 0..7
    int fr   = lane & 15;
    int quad = lane >> 4;
    int sw   = fr & 7;

    int j0 = cg * 32;
    int row_base = mt * 128 + w * 16;   // wave owns 16 rows

    const short* Wd = w_hh + (size_t)d * G3 * HH;
    const short* hb = hbf_in + (size_t)d * NBAT * HH;

    // ---- stage W phase 0 (cols j0..j0+16) into LDS (swizzled src, linear dest) ----
    #pragma unroll
    for (int q = 0; q < 12; ++q) {
        int c  = w * 12 + q;               // 0..95
        int rr = c >> 1, kh = c & 1;       // rr: wrow 0..47, kh: half-row
        int g  = rr >> 4, jc = rr & 15;
        const short* src = Wd + (size_t)(g * HH + j0 + jc) * HH
                         + (size_t)(kh * 64 + (lane ^ (rr & 7))) * 8;
        GLOAD16(src, &Ws[rr * 1024 + kh * 512]);
    }

    // ---- A fully into registers: 32 x s16x8 (row = row_base+fr, k-slice quad*8) ----
    const short* asrc = hb + (size_t)(row_base + fr) * HH + quad * 8;
    s16x8 areg[32];
    #pragma unroll
    for (int c = 0; c < 32; ++c)
        areg[c] = *(const s16x8*)(asrc + c * 32);

    f32x4 acc[2][3];
    #pragma unroll
    for (int p = 0; p < 2; ++p)
        #pragma unroll
        for (int g = 0; g < 3; ++g)
            acc[p][g] = (f32x4){0.f, 0.f, 0.f, 0.f};

    __syncthreads();   // drains W0 DMA + A loads

    // ---- phase 0 K-loop: pure registers + LDS ----
    #pragma unroll
    for (int c = 0; c < 32; ++c) {
        int ks = c * 4 + quad;
        #pragma unroll
        for (int g = 0; g < 3; ++g) {
            s16x8 bg = *(const s16x8*)&Ws[(g * 16 + fr) * 1024 + ((ks ^ sw) << 3)];
            acc[0][g] = __builtin_amdgcn_mfma_f32_16x16x32_bf16(areg[c], bg, acc[0][g], 0, 0, 0);
        }
    }

    __syncthreads();   // all waves done reading Ws phase 0

    // ---- stage W phase 1 (cols j0+16..j0+32) ----
    #pragma unroll
    for (int q = 0; q < 12; ++q) {
        int c  = w * 12 + q;
        int rr = c >> 1, kh = c & 1;
        int g  = rr >> 4, jc = rr & 15;
        const short* src = Wd + (size_t)(g * HH + j0 + 16 + jc) * HH
                         + (size_t)(kh * 64 + (lane ^ (rr & 7))) * 8;
        GLOAD16(src, &Ws[rr * 1024 + kh * 512]);
    }

    // ---- gi (fp16), h master, biases for BOTH phases: issued here so their
    // latency hides under W1 staging + phase-1 MFMAs, and phase-0's register
    // peak excludes them (spill avoidance) ----
    float gir[2][4], giz[2][4], gin[2][4], hreg[2][4];
    float bhr[2], bhz[2], bhn[2];
    #pragma unroll
    for (int p = 0; p < 2; ++p) {
        int jcol = j0 + p * 16 + fr;
        bhr[p] = b_hh[d * G3 + jcol];
        bhz[p] = b_hh[d * G3 + HH + jcol];
        bhn[p] = b_hh[d * G3 + 2 * HH + jcol];
        size_t gb = ((size_t)d * Mchunk + (size_t)ttl * NBAT) * G3 + jcol;
        #pragma unroll
        for (int r = 0; r < 4; ++r) {
            int n = row_base + quad * 4 + r;
            size_t gg = gb + (size_t)n * G3;
            gir[p][r] = __half2float(gi[gg]);
            giz[p][r] = __half2float(gi[gg + HH]);
            gin[p][r] = __half2float(gi[gg + 2 * HH]);
            hreg[p][r] = h[((size_t)d * NBAT + n) * HH + jcol];
        }
    }

    __syncthreads();   // drains W1 DMA (scalar loads waited at use)

    // ---- phase 1 K-loop: A reused from registers ----
    #pragma unroll
    for (int c = 0; c < 32; ++c) {
        int ks = c * 4 + quad;
        #pragma unroll
        for (int g = 0; g < 3; ++g) {
            s16x8 bg = *(const s16x8*)&Ws[(g * 16 + fr) * 1024 + ((ks ^ sw) << 3)];
            acc[1][g] = __builtin_amdgcn_mfma_f32_16x16x32_bf16(areg[c], bg, acc[1][g], 0, 0, 0);
        }
    }

    // ---- gates + state update (both phases) ----
    short* ho = hbf_out + (size_t)d * NBAT * HH;
    #pragma unroll
    for (int p = 0; p < 2; ++p) {
        int jcol = j0 + p * 16 + fr;
        #pragma unroll
        for (int r = 0; r < 4; ++r) {
            int n = row_base + quad * 4 + r;
            float hrv = acc[p][0][r] + bhr[p];
            float hzv = acc[p][1][r] + bhz[p];
            float hnv = acc[p][2][r] + bhn[p];
            float rg = 1.f / (1.f + __expf(-(gir[p][r] + hrv)));
            float zg = 1.f / (1.f + __expf(-(giz[p][r] + hzv)));
            float ng = tanhf(gin[p][r] + rg * hnv);
            float hnew = (1.f - zg) * ng + zg * hreg[p][r];
            h[((size_t)d * NBAT + n) * HH + jcol] = hnew;
            ho[(size_t)n * HH + jcol] = f2bf(hnew);
            size_t eidx = ((size_t)n * TT + t) * ENC_W + (size_t)d * HH + jcol;
            if (enc_bf) enc_bf[eidx] = f2bf(hnew);
            if (enc)    enc[eidx]    = hnew;
        }
    }
}

// ---------------- FC head ----------------
__global__ void bigru_fc(const float* __restrict__ enc, const float* __restrict__ fc_w,
                         const float* __restrict__ fc_b, float* __restrict__ out) {
    int n = blockIdx.x;
    int tid = threadIdx.x;
    __shared__ float hbuf[ENC_W];
    for (int k = tid; k < ENC_W; k += blockDim.x)
        hbuf[k] = enc[(size_t)n * TT * ENC_W + (size_t)(TT - 1) * ENC_W + k];
    __syncthreads();
    if (tid < NCLS) {
        float acc = fc_b[tid];
        for (int k = 0; k < ENC_W; ++k)
            acc += hbuf[k] * fc_w[(size_t)tid * ENC_W + k];
        out[(size_t)n * NCLS + tid] = acc;
    }
}

extern "C" void kernel_launch(void* const* d_in, const int* in_sizes, int n_in,
                              void* d_out, int out_size, void* d_ws, size_t ws_size,
                              hipStream_t stream) {
    const float* x        = (const float*)d_in[0];
    const float* bn_gamma = (const float*)d_in[1];
    const float* bn_beta  = (const float*)d_in[2];
    const float* w_ih[3]  = {(const float*)d_in[3], (const float*)d_in[7],  (const float*)d_in[11]};
    const float* w_hh[3]  = {(const float*)d_in[4], (const float*)d_in[8],  (const float*)d_in[12]};
    const float* b_ih[3]  = {(const float*)d_in[5], (const float*)d_in[9],  (const float*)d_in[13]};
    const float* b_hh[3]  = {(const float*)d_in[6], (const float*)d_in[10], (const float*)d_in[14]};
    const float* fc_w     = (const float*)d_in[15];
    const float* fc_b     = (const float*)d_in[16];

    float* out = (float*)d_out;
    float* enc = out + NBAT * NCLS;                       // [256][64][2048] fp32

    // ---- workspace bump allocator (256B aligned) ----
    char* base = (char*)d_ws;
    size_t off = 0;
    auto alloc = [&](size_t bytes) {
        void* p = base + off;
        off += (bytes + 255) & ~(size_t)255;
        return p;
    };
    float* mean      = (float*)alloc(IN0 * 4);
    float* istd      = (float*)alloc(IN0 * 4);
    short* xn_bf     = (short*)alloc((size_t)NBAT * TT * IN0P * 2);
    short* wih0_bf   = (short*)alloc((size_t)2 * G3 * IN0P * 2);
    short* wih_bf    = (short*)alloc((size_t)2 * G3 * ENC_W * 2);
    short* whh_bf    = (short*)alloc((size_t)2 * G3 * HH * 2);
    float* h         = (float*)alloc((size_t)2 * NBAT * HH * 4);
    short* hbf       = (short*)alloc((size_t)2 * 2 * NBAT * HH * 2);  // double buffer
    short* enc_bf    = (short*)alloc((size_t)NBAT * TT * ENC_W * 2);
    size_t fixed = off;

    // pick largest Tc whose fp16 gi chunk fits in remaining ws
    int Tc = 1;
    for (int cand : {16, 8, 4, 2, 1}) {
        size_t gi_bytes = (size_t)2 * NBAT * cand * G3 * 2;
        if (fixed + gi_bytes + 1024 <= ws_size) { Tc = cand; break; }
    }
    __half* gi = (__half*)alloc((size_t)2 * NBAT * Tc * G3 * 2);
    int Mchunk = NBAT * Tc;

    // ---- BN ----
    bigru_bn_stats<<<IN0, 256, 0, stream>>>(x, mean, istd);
    bigru_bn_apply_bf16<<<(NBAT * TT * IN0P + 255) / 256, 256, 0, stream>>>(
        x, mean, istd, bn_gamma, bn_beta, xn_bf);

    // ---- weight conversions (layer-0 padded) ----
    bigru_cvt_wih0<<<(2 * G3 * IN0P + 255) / 256, 256, 0, stream>>>(w_ih[0], wih0_bf);

    for (int l = 0; l < 3; ++l) {
        if (l > 0) {
            int n4 = (2 * G3 * ENC_W) / 4;
            bigru_cvt4<<<(n4 + 255) / 256, 256, 0, stream>>>(w_ih[l], wih_bf, n4);
        }
        {
            int n4 = (2 * G3 * HH) / 4;
            bigru_cvt4<<<(n4 + 255) / 256, 256, 0, stream>>>(w_hh[l], whh_bf, n4);
        }
        hipMemsetAsync(h, 0, (size_t)2 * NBAT * HH * 4, stream);
        hipMemsetAsync(hbf, 0, (size_t)2 * 2 * NBAT * HH * 2, stream);

        const short* Abase = (l == 0) ? xn_bf : enc_bf;
        int ldA = (l == 0) ? IN0P : ENC_W;
        int K   = (l == 0) ? IN0P : ENC_W;
        const short* W = (l == 0) ? wih0_bf : wih_bf;
        float* enc_out   = (l == 2) ? enc : nullptr;
        short* encbf_out = (l == 2) ? nullptr : enc_bf;

        for (int t0 = 0; t0 < TT; t0 += Tc) {
            bigru_gi_gemm<<<dim3(G3 / 128, Mchunk / 128, 2), 256, 0, stream>>>(
                Abase, ldA, K, W, b_ih[l], gi, t0, Mchunk);

            for (int tt = 0; tt < Tc; ++tt) {
                int t = t0 + tt;
                const short* hin = hbf + (size_t)(t & 1) * 2 * NBAT * HH;
                short*       hout = hbf + (size_t)((t + 1) & 1) * 2 * NBAT * HH;
                bigru_step<<<dim3(128), 512, 0, stream>>>(
                    whh_bf, b_hh[l], gi, h, hin, hout,
                    enc_out, encbf_out, t, tt, Mchunk);
            }
        }
    }

    bigru_fc<<<NBAT, 256, 0, stream>>>(enc, fc_w, fc_b, out);
}